// Round 2
// baseline (3319.044 us; speedup 1.0000x reference)
//
#include <hip/hip_runtime.h>
#include <hip/hip_bf16.h>

#define HD 512      // d_model
#define NST 64      // d_state
#define NLAY 6
#define LSEQ 784
#define BB 64       // batch
#define NPASS 32    // complex states per lane (lane pairs cover all 64)

// ---------------------------------------------------------------------------
// Precompute lambda = exp(dt*A) and 2*Cd (ZOH-discretized C) per (layer,n,h),
// stored [layer][n][h] so scan lanes (consecutive h) load coalesced.
// ---------------------------------------------------------------------------
__global__ void precompute_k(const float* __restrict__ log_dt,
                             const float* __restrict__ log_A_real,
                             const float* __restrict__ A_imag,
                             const float* __restrict__ C_re,
                             const float* __restrict__ C_im,
                             float* __restrict__ lamr, float* __restrict__ lami,
                             float* __restrict__ cdr,  float* __restrict__ cdi)
{
    int t = blockIdx.x * blockDim.x + threadIdx.x;
    if (t >= NLAY * HD * NST) return;
    int n  = t % NST;
    int ih = t / NST;          // i*HD + h
    int i  = ih / HD;
    int h  = ih % HD;

    float dt  = expf(log_dt[ih]);
    float are = -expf(log_A_real[t]);
    float aim = A_imag[t];
    float dr = are * dt, di = aim * dt;
    float er = expf(dr);
    float sn, cs;
    __sincosf(di, &sn, &cs);          // di = pi*n*dt <= pi*63*0.1 ~ 20, fine
    float lr = er * cs, li = er * sn;  // lambda = exp(dt*A)
    // q = (lambda - 1) / A
    float e1r = lr - 1.0f, e1i = li;
    float den = are * are + aim * aim;
    float qr = (e1r * are + e1i * aim) / den;
    float qi = (e1i * are - e1r * aim) / den;
    float crv = C_re[t], civ = C_im[t];
    float cdre = crv * qr - civ * qi;
    float cdim = crv * qi + civ * qr;

    size_t o = ((size_t)i * NST + n) * HD + h;
    lamr[o] = lr; lami[o] = li;
    cdr[o] = 2.0f * cdre; cdi[o] = 2.0f * cdim;  // fold the 2*Re() factor
}

// ---------------------------------------------------------------------------
// Encoder: u[b,l,h] = x[b,l] * enc_w[h] + enc_b[h]
// ---------------------------------------------------------------------------
__global__ void encoder_k(const float* __restrict__ x, const float* __restrict__ ew,
                          const float* __restrict__ eb, float* __restrict__ u)
{
    size_t g = (size_t)blockIdx.x * blockDim.x + threadIdx.x;
    if (g >= (size_t)BB * LSEQ * HD) return;
    int h = (int)(g % HD);
    size_t bl = g / HD;
    u[g] = fmaf(x[bl], ew[h], eb[h]);
}

// ---------------------------------------------------------------------------
// Fused SSM scan + residual, IN PLACE on u.
// Lane pair = one (b,h) channel; even lane holds states 0..31, odd 32..63.
// s_l = lam*s_{l-1} + u_l ; y_l = sum 2*Re(Cd*s_l) (halves combined by
// shfl_xor(1)); then u_l <- u_l*(1+D[h]) + y_l  (the pre-LN residual value).
// In-place safety: each address is loaded (both lanes, iter l / prefetch
// l+2) strictly before the even lane's store at iter l — same wave,
// program order. Different channels touch disjoint addresses.
// ---------------------------------------------------------------------------
__global__ __launch_bounds__(256, 1)
void scan_k(float* __restrict__ u,
            const float* __restrict__ lamr, const float* __restrict__ lami,
            const float* __restrict__ cdr,  const float* __restrict__ cdi,
            const float* __restrict__ Dvec)
{
    int g = blockIdx.x * 256 + threadIdx.x;   // 0 .. BB*HD*2-1
    int ch = g >> 1;                          // (b,h) flat
    int half = g & 1;
    int h = ch & (HD - 1);
    int b = ch >> 9;                          // HD = 512
    int n0 = half * NPASS;
    float dcoef = 1.0f + Dvec[h];

    float lr[NPASS], li[NPASS], cr[NPASS], ci[NPASS], sr[NPASS], si[NPASS];
#pragma unroll
    for (int n = 0; n < NPASS; n++) {
        size_t o = (size_t)(n0 + n) * HD + h;
        lr[n] = lamr[o]; li[n] = lami[o];
        cr[n] = cdr[o];  ci[n] = cdi[o];
        sr[n] = 0.f; si[n] = 0.f;
    }

    size_t idx = (size_t)b * LSEQ * HD + h;
    float u0 = u[idx];
    float u1 = u[idx + HD];
#pragma unroll 1
    for (int l = 0; l < LSEQ; l++) {
        float uv = u0;
        u0 = u1;
        if (l + 2 < LSEQ) u1 = u[idx + 2 * HD];   // prefetch depth 2
        float ya = 0.f, yb = 0.f;
#pragma unroll
        for (int n = 0; n < NPASS; n++) {
            float t0  = fmaf(-li[n], si[n], uv);
            float nsr = fmaf(lr[n], sr[n], t0);
            float nsi = fmaf(lr[n], si[n], li[n] * sr[n]);
            sr[n] = nsr; si[n] = nsi;
            ya = fmaf(cr[n], nsr, ya);
            yb = fmaf(ci[n], nsi, yb);
        }
        float y = ya - yb;
        y += __shfl_xor(y, 1, 64);                // combine state halves
        if (half == 0) u[idx] = fmaf(uv, dcoef, y);
        idx += HD;
    }
}

// ---------------------------------------------------------------------------
// In-place LayerNorm over H. One wave per (b,l) row; 8 floats per lane.
// ---------------------------------------------------------------------------
__global__ void ln_k(float* __restrict__ u, const float* __restrict__ gp,
                     const float* __restrict__ bp)
{
    int wid  = threadIdx.x >> 6;
    int lane = threadIdx.x & 63;
    size_t row = (size_t)blockIdx.x * 4 + wid;   // < BB*LSEQ exactly
    float* up = u + row * HD;

    float4 a0 = ((const float4*)up)[lane];
    float4 a1 = ((const float4*)up)[64 + lane];
    float v[8] = {a0.x, a0.y, a0.z, a0.w, a1.x, a1.y, a1.z, a1.w};
    int h0 = lane * 4, h1 = 256 + lane * 4;

    float s = 0.f;
#pragma unroll
    for (int j = 0; j < 8; j++) s += v[j];
#pragma unroll
    for (int m = 32; m >= 1; m >>= 1) s += __shfl_xor(s, m, 64);
    float mu = s * (1.0f / HD);

    float q = 0.f;
#pragma unroll
    for (int j = 0; j < 8; j++) { float d = v[j] - mu; q += d * d; }
#pragma unroll
    for (int m = 32; m >= 1; m >>= 1) q += __shfl_xor(q, m, 64);
    float rs = rsqrtf(q * (1.0f / HD) + 1e-5f);

    float o[8];
#pragma unroll
    for (int j = 0; j < 8; j++) {
        int h = (j < 4) ? (h0 + j) : (h1 + j - 4);
        o[j] = fmaf((v[j] - mu) * rs, gp[h], bp[h]);
    }
    ((float4*)up)[lane]      = {o[0], o[1], o[2], o[3]};
    ((float4*)up)[64 + lane] = {o[4], o[5], o[6], o[7]};
}

// ---------------------------------------------------------------------------
// Mean-pool over L: pooled[b,h] = mean_l u[b,l,h]  (lane h: contiguous 256B
// row chunks -> coalesced)
// ---------------------------------------------------------------------------
__global__ void pool_k(const float* __restrict__ u, float* __restrict__ p)
{
    int g = blockIdx.x * blockDim.x + threadIdx.x;
    if (g >= BB * HD) return;
    int h = g & (HD - 1);
    int b = g >> 9;
    const float* up = u + (size_t)b * LSEQ * HD + h;
    float s = 0.f;
    for (int l = 0; l < LSEQ; l++) s += up[(size_t)l * HD];
    p[g] = s * (1.0f / LSEQ);
}

// ---------------------------------------------------------------------------
// Decoder: out[b,c] = pooled[b,:] @ dec_w[:,c] + dec_b[c]
// ---------------------------------------------------------------------------
__global__ void dec_k(const float* __restrict__ p, const float* __restrict__ w,
                      const float* __restrict__ bias, float* __restrict__ out)
{
    int t = blockIdx.x * blockDim.x + threadIdx.x;
    if (t >= BB * 10) return;
    int c = t % 10, b = t / 10;
    float acc = bias[c];
    const float* pb = p + b * HD;
    for (int h = 0; h < HD; h++) acc = fmaf(pb[h], w[h * 10 + c], acc);
    out[t] = acc;
}

// ---------------------------------------------------------------------------
extern "C" void kernel_launch(void* const* d_in, const int* in_sizes, int n_in,
                              void* d_out, int out_size, void* d_ws, size_t ws_size,
                              hipStream_t stream)
{
    const float* x   = (const float*)d_in[0];
    const float* ew  = (const float*)d_in[1];
    const float* eb  = (const float*)d_in[2];
    const float* ldt = (const float*)d_in[3];
    const float* lar = (const float*)d_in[4];
    const float* aim = (const float*)d_in[5];
    const float* cre = (const float*)d_in[6];
    const float* cim = (const float*)d_in[7];
    const float* Dp  = (const float*)d_in[8];
    const float* lng = (const float*)d_in[9];
    const float* lnb = (const float*)d_in[10];
    const float* fng = (const float*)d_in[11];
    const float* fnb = (const float*)d_in[12];
    const float* dw  = (const float*)d_in[13];
    const float* db  = (const float*)d_in[14];
    float* out = (float*)d_out;

    float* ws = (float*)d_ws;
    const size_t SZ = (size_t)BB * LSEQ * HD;   // 25,690,112 floats (103 MB)
    const size_t P  = (size_t)NLAY * NST * HD;  // 196,608 floats
    float* U  = ws;                              // residual stream, in-place
    float* LR = ws + SZ;
    float* LI = LR + P;
    float* CR = LI + P;
    float* CI = CR + P;
    float* PO = CI + P;                          // BB*HD floats
    // total: SZ + 4P + BB*HD = 26,509,312 floats = 106.0 MB

    precompute_k<<<(NLAY * HD * NST + 255) / 256, 256, 0, stream>>>(
        ldt, lar, aim, cre, cim, LR, LI, CR, CI);
    encoder_k<<<(int)((SZ + 255) / 256), 256, 0, stream>>>(x, ew, eb, U);

    for (int i = 0; i < NLAY; i++) {
        size_t po = (size_t)i * NST * HD;
        scan_k<<<BB * HD * 2 / 256, 256, 0, stream>>>(
            U, LR + po, LI + po, CR + po, CI + po, Dp + i * HD);
        ln_k<<<BB * LSEQ / 4, 256, 0, stream>>>(U, lng + i * HD, lnb + i * HD);
    }
    ln_k<<<BB * LSEQ / 4, 256, 0, stream>>>(U, fng, fnb);
    pool_k<<<BB * HD / 256, 256, 0, stream>>>(U, PO);
    dec_k<<<(BB * 10 + 255) / 256, 256, 0, stream>>>(PO, dw, db, out);
}

// Round 3
// 2161.899 us; speedup vs baseline: 1.5352x; 1.5352x over previous
//
#include <hip/hip_runtime.h>
#include <hip/hip_bf16.h>

#define HD 512      // d_model
#define NST 64      // d_state
#define NLAY 6
#define LSEQ 784
#define BB 64       // batch
#define QL 4        // lanes per channel
#define NPASS (NST / QL)   // 16 complex states per lane

// ---------------------------------------------------------------------------
// Precompute lambda = exp(dt*A) and 2*Cd (ZOH-discretized C) per (layer,n,h),
// stored [layer][n][h] so scan lanes (consecutive h) load coalesced.
// ---------------------------------------------------------------------------
__global__ void precompute_k(const float* __restrict__ log_dt,
                             const float* __restrict__ log_A_real,
                             const float* __restrict__ A_imag,
                             const float* __restrict__ C_re,
                             const float* __restrict__ C_im,
                             float* __restrict__ lamr, float* __restrict__ lami,
                             float* __restrict__ cdr,  float* __restrict__ cdi)
{
    int t = blockIdx.x * blockDim.x + threadIdx.x;
    if (t >= NLAY * HD * NST) return;
    int n  = t % NST;
    int ih = t / NST;          // i*HD + h
    int i  = ih / HD;
    int h  = ih % HD;

    float dt  = expf(log_dt[ih]);
    float are = -expf(log_A_real[t]);
    float aim = A_imag[t];
    float dr = are * dt, di = aim * dt;
    float er = expf(dr);
    float sn, cs;
    __sincosf(di, &sn, &cs);
    float lr = er * cs, li = er * sn;  // lambda = exp(dt*A)
    // q = (lambda - 1) / A
    float e1r = lr - 1.0f, e1i = li;
    float den = are * are + aim * aim;
    float qr = (e1r * are + e1i * aim) / den;
    float qi = (e1i * are - e1r * aim) / den;
    float crv = C_re[t], civ = C_im[t];
    float cdre = crv * qr - civ * qi;
    float cdim = crv * qi + civ * qr;

    size_t o = ((size_t)i * NST + n) * HD + h;
    lamr[o] = lr; lami[o] = li;
    cdr[o] = 2.0f * cdre; cdi[o] = 2.0f * cdim;  // fold the 2*Re() factor
}

// ---------------------------------------------------------------------------
// Encoder: u[b,l,h] = x[b,l] * enc_w[h] + enc_b[h]
// ---------------------------------------------------------------------------
__global__ void encoder_k(const float* __restrict__ x, const float* __restrict__ ew,
                          const float* __restrict__ eb, float* __restrict__ u)
{
    size_t g = (size_t)blockIdx.x * blockDim.x + threadIdx.x;
    if (g >= (size_t)BB * LSEQ * HD) return;
    int h = (int)(g % HD);
    size_t bl = g / HD;
    u[g] = fmaf(x[bl], ew[h], eb[h]);
}

// ---------------------------------------------------------------------------
// Fused SSM scan + residual, IN PLACE on u.
// QL=4 lanes per (b,h) channel; lane quarter q holds states q*16..q*16+15.
// s_l = lam*s_{l-1} + u_l ; y_l = sum 2*Re(Cd*s_l) (quarters combined via
// shfl_xor 1,2); then u_l <- u_l*(1+D[h]) + y_l  (pre-LN residual value).
// In-place safety: every load of an address (incl. depth-2 prefetch)
// precedes the owning lane's store to it in wave program order; channels
// are address-disjoint across waves.
// 2048 waves -> 2 waves/SIMD (launch_bounds(256,2) = 2 blocks/CU).
// ---------------------------------------------------------------------------
__global__ __launch_bounds__(256, 2)
void scan_k(float* __restrict__ u,
            const float* __restrict__ lamr, const float* __restrict__ lami,
            const float* __restrict__ cdr,  const float* __restrict__ cdi,
            const float* __restrict__ Dvec)
{
    int g = blockIdx.x * 256 + threadIdx.x;   // 0 .. BB*HD*QL-1
    int ch = g >> 2;                          // (b,h) flat
    int quarter = g & 3;
    int h = ch & (HD - 1);
    int b = ch >> 9;                          // HD = 512
    int n0 = quarter * NPASS;
    float dcoef = 1.0f + Dvec[h];

    float lr[NPASS], li[NPASS], cr[NPASS], ci[NPASS], sr[NPASS], si[NPASS];
#pragma unroll
    for (int n = 0; n < NPASS; n++) {
        size_t o = (size_t)(n0 + n) * HD + h;
        lr[n] = lamr[o]; li[n] = lami[o];
        cr[n] = cdr[o];  ci[n] = cdi[o];
        sr[n] = 0.f; si[n] = 0.f;
    }

    size_t idx = (size_t)b * LSEQ * HD + h;
    float u0 = u[idx];
    float u1 = u[idx + HD];
#pragma unroll 2
    for (int l = 0; l < LSEQ; l++) {
        float uv = u0;
        u0 = u1;
        u1 = u[idx + 2 * HD];   // depth-2 prefetch; U has 2*HD slack at end
        float ya = 0.f, yb = 0.f;
#pragma unroll
        for (int n = 0; n < NPASS; n++) {
            float t0  = fmaf(-li[n], si[n], uv);
            float nsr = fmaf(lr[n], sr[n], t0);
            float nsi = fmaf(lr[n], si[n], li[n] * sr[n]);
            sr[n] = nsr; si[n] = nsi;
            ya = fmaf(cr[n], nsr, ya);
            yb = fmaf(ci[n], nsi, yb);
        }
        float y = ya - yb;
        y += __shfl_xor(y, 1, 64);                // combine 4 state quarters
        y += __shfl_xor(y, 2, 64);
        if (quarter == 0) u[idx] = fmaf(uv, dcoef, y);
        idx += HD;
    }
}

// ---------------------------------------------------------------------------
// In-place LayerNorm over H. One wave per (b,l) row; 8 floats per lane.
// ---------------------------------------------------------------------------
__global__ void ln_k(float* __restrict__ u, const float* __restrict__ gp,
                     const float* __restrict__ bp)
{
    int wid  = threadIdx.x >> 6;
    int lane = threadIdx.x & 63;
    size_t row = (size_t)blockIdx.x * 4 + wid;   // < BB*LSEQ exactly
    float* up = u + row * HD;

    float4 a0 = ((const float4*)up)[lane];
    float4 a1 = ((const float4*)up)[64 + lane];
    float v[8] = {a0.x, a0.y, a0.z, a0.w, a1.x, a1.y, a1.z, a1.w};
    int h0 = lane * 4, h1 = 256 + lane * 4;

    float s = 0.f;
#pragma unroll
    for (int j = 0; j < 8; j++) s += v[j];
#pragma unroll
    for (int m = 32; m >= 1; m >>= 1) s += __shfl_xor(s, m, 64);
    float mu = s * (1.0f / HD);

    float q = 0.f;
#pragma unroll
    for (int j = 0; j < 8; j++) { float d = v[j] - mu; q += d * d; }
#pragma unroll
    for (int m = 32; m >= 1; m >>= 1) q += __shfl_xor(q, m, 64);
    float rs = rsqrtf(q * (1.0f / HD) + 1e-5f);

    float o[8];
#pragma unroll
    for (int j = 0; j < 8; j++) {
        int h = (j < 4) ? (h0 + j) : (h1 + j - 4);
        o[j] = fmaf((v[j] - mu) * rs, gp[h], bp[h]);
    }
    ((float4*)up)[lane]      = {o[0], o[1], o[2], o[3]};
    ((float4*)up)[64 + lane] = {o[4], o[5], o[6], o[7]};
}

// ---------------------------------------------------------------------------
// Mean-pool over L: pooled[b,h] = mean_l u[b,l,h]
// ---------------------------------------------------------------------------
__global__ void pool_k(const float* __restrict__ u, float* __restrict__ p)
{
    int g = blockIdx.x * blockDim.x + threadIdx.x;
    if (g >= BB * HD) return;
    int h = g & (HD - 1);
    int b = g >> 9;
    const float* up = u + (size_t)b * LSEQ * HD + h;
    float s = 0.f;
    for (int l = 0; l < LSEQ; l++) s += up[(size_t)l * HD];
    p[g] = s * (1.0f / LSEQ);
}

// ---------------------------------------------------------------------------
// Decoder: out[b,c] = pooled[b,:] @ dec_w[:,c] + dec_b[c]
// ---------------------------------------------------------------------------
__global__ void dec_k(const float* __restrict__ p, const float* __restrict__ w,
                      const float* __restrict__ bias, float* __restrict__ out)
{
    int t = blockIdx.x * blockDim.x + threadIdx.x;
    if (t >= BB * 10) return;
    int c = t % 10, b = t / 10;
    float acc = bias[c];
    const float* pb = p + b * HD;
    for (int h = 0; h < HD; h++) acc = fmaf(pb[h], w[h * 10 + c], acc);
    out[t] = acc;
}

// ---------------------------------------------------------------------------
extern "C" void kernel_launch(void* const* d_in, const int* in_sizes, int n_in,
                              void* d_out, int out_size, void* d_ws, size_t ws_size,
                              hipStream_t stream)
{
    const float* x   = (const float*)d_in[0];
    const float* ew  = (const float*)d_in[1];
    const float* eb  = (const float*)d_in[2];
    const float* ldt = (const float*)d_in[3];
    const float* lar = (const float*)d_in[4];
    const float* aim = (const float*)d_in[5];
    const float* cre = (const float*)d_in[6];
    const float* cim = (const float*)d_in[7];
    const float* Dp  = (const float*)d_in[8];
    const float* lng = (const float*)d_in[9];
    const float* lnb = (const float*)d_in[10];
    const float* fng = (const float*)d_in[11];
    const float* fnb = (const float*)d_in[12];
    const float* dw  = (const float*)d_in[13];
    const float* db  = (const float*)d_in[14];
    float* out = (float*)d_out;

    float* ws = (float*)d_ws;
    const size_t SZ = (size_t)BB * LSEQ * HD;   // 25,690,112 floats (103 MB)
    const size_t P  = (size_t)NLAY * NST * HD;  // 196,608 floats
    float* U  = ws;                              // residual stream, in-place
    float* LR = ws + SZ + 2 * HD;                // 2*HD slack for prefetch
    float* LI = LR + P;
    float* CR = LI + P;
    float* CI = CR + P;
    float* PO = CI + P;                          // BB*HD floats
    // total: ~106 MB

    precompute_k<<<(NLAY * HD * NST + 255) / 256, 256, 0, stream>>>(
        ldt, lar, aim, cre, cim, LR, LI, CR, CI);
    encoder_k<<<(int)((SZ + 255) / 256), 256, 0, stream>>>(x, ew, eb, U);

    for (int i = 0; i < NLAY; i++) {
        size_t po = (size_t)i * NST * HD;
        scan_k<<<BB * HD * QL / 256, 256, 0, stream>>>(
            U, LR + po, LI + po, CR + po, CI + po, Dp + i * HD);
        ln_k<<<BB * LSEQ / 4, 256, 0, stream>>>(U, lng + i * HD, lnb + i * HD);
    }
    ln_k<<<BB * LSEQ / 4, 256, 0, stream>>>(U, fng, fnb);
    pool_k<<<BB * HD / 256, 256, 0, stream>>>(U, PO);
    dec_k<<<(BB * 10 + 255) / 256, 256, 0, stream>>>(PO, dw, db, out);
}